// Round 1
// baseline (2991.899 us; speedup 1.0000x reference)
//
#include <hip/hip_runtime.h>

#define NN 100000   // nodes
#define NE 500000   // edges per relation
#define NR 4        // relations
#define NL 4        // layers
#define FIN 64      // input features
#define D 128       // embedding dim
#define NGR 64      // graphs

// ---------------- utility ----------------
__global__ void zero_i32(int* __restrict__ p, int n) {
    int i = blockIdx.x * blockDim.x + threadIdx.x;
    if (i < n) p[i] = 0;
}
__global__ void zero_f32(float* __restrict__ p, int n) {
    int i = blockIdx.x * blockDim.x + threadIdx.x;
    if (i < n) p[i] = 0.f;
}

// ---------------- CSR build (dst-indexed), done once per launch ----------------
__global__ void count_kernel(const int* __restrict__ dst, int* __restrict__ cnt) {
    int e = blockIdx.x * blockDim.x + threadIdx.x;
    if (e < NE) atomicAdd(&cnt[dst[e]], 1);
}

// one block (1024 threads) per relation: exclusive scan of counts -> offs,
// and rewrite counts[] in-place as the running cursor for fill_kernel.
__global__ void scan_kernel(int* __restrict__ counts, int* __restrict__ offs) {
    const int r = blockIdx.x;
    int* cnt = counts + (size_t)r * NN;
    int* off = offs + (size_t)r * (NN + 1);
    const int CH = (NN + 1023) / 1024;  // 98
    int t = threadIdx.x;
    int lo = t * CH;
    int hi = lo + CH; if (hi > NN) hi = NN; if (lo > NN) lo = NN;
    int s = 0;
    for (int i = lo; i < hi; i++) s += cnt[i];
    __shared__ int sd[1024];
    sd[t] = s;
    __syncthreads();
    for (int d = 1; d < 1024; d <<= 1) {
        int v = (t >= d) ? sd[t - d] : 0;
        __syncthreads();
        sd[t] += v;
        __syncthreads();
    }
    int run = sd[t] - s;  // exclusive base for this chunk
    for (int i = lo; i < hi; i++) {
        int c = cnt[i];
        off[i] = run;
        cnt[i] = run;   // becomes cursor
        run += c;
    }
    if (t == 1023) off[NN] = run;  // == NE
}

__global__ void fill_kernel(const int* __restrict__ src, const int* __restrict__ dst,
                            int* __restrict__ cur, int* __restrict__ esrc) {
    int e = blockIdx.x * blockDim.x + threadIdx.x;
    if (e < NE) {
        int pos = atomicAdd(&cur[dst[e]], 1);
        esrc[pos] = src[e];
    }
}

// ---------------- GEMM: out[n,c] = A[n,:K] @ W[K,128] (+ bias) ----------------
// W staged in LDS (K*128*4 B <= 64 KB). A rows read once from global (float4).
// 256 threads: cg = tid&31 -> cols 4cg..4cg+3 ; ng = tid>>5 -> 4 nodes each.
// Block tile = 32 nodes x 128 cols, grid-stride over 3125 tiles.
template <int K>
__global__ __launch_bounds__(256) void gemm_kernel(const float* __restrict__ A,
                                                   const float* __restrict__ W,
                                                   const float* __restrict__ bias,
                                                   float* __restrict__ out) {
    __shared__ float Ws[K * D];
    const int tid = threadIdx.x;
    for (int i = tid; i < K * D / 4; i += 256)
        ((float4*)Ws)[i] = ((const float4*)W)[i];
    const int cg = tid & 31;
    const int ng = tid >> 5;
    float bv[4] = {0.f, 0.f, 0.f, 0.f};
    if (bias) {
        float4 b4 = ((const float4*)bias)[cg];
        bv[0] = b4.x; bv[1] = b4.y; bv[2] = b4.z; bv[3] = b4.w;
    }
    __syncthreads();
    for (int tile = blockIdx.x; tile < NN / 32; tile += gridDim.x) {
        const int node0 = tile * 32 + ng * 4;
        const float4* A0 = (const float4*)(A + (size_t)node0 * K);
        float acc[4][4];
#pragma unroll
        for (int j = 0; j < 4; j++)
#pragma unroll
            for (int c = 0; c < 4; c++) acc[j][c] = bv[c];
#pragma unroll 4
        for (int k4 = 0; k4 < K / 4; k4++) {
            float a[4][4], w[4][4];
            *(float4*)a[0] = A0[0 * (K / 4) + k4];
            *(float4*)a[1] = A0[1 * (K / 4) + k4];
            *(float4*)a[2] = A0[2 * (K / 4) + k4];
            *(float4*)a[3] = A0[3 * (K / 4) + k4];
            *(float4*)w[0] = *(const float4*)&Ws[(k4 * 4 + 0) * D + cg * 4];
            *(float4*)w[1] = *(const float4*)&Ws[(k4 * 4 + 1) * D + cg * 4];
            *(float4*)w[2] = *(const float4*)&Ws[(k4 * 4 + 2) * D + cg * 4];
            *(float4*)w[3] = *(const float4*)&Ws[(k4 * 4 + 3) * D + cg * 4];
#pragma unroll
            for (int kk = 0; kk < 4; kk++)
#pragma unroll
                for (int j = 0; j < 4; j++)
#pragma unroll
                    for (int c = 0; c < 4; c++) acc[j][c] += a[j][kk] * w[kk][c];
        }
#pragma unroll
        for (int j = 0; j < 4; j++) {
            float4 o = make_float4(acc[j][0], acc[j][1], acc[j][2], acc[j][3]);
            ((float4*)(out + (size_t)(node0 + j) * D))[cg] = o;
        }
    }
}

// ---------------- aggregation: out[n] = base[n] + (deg>0 ? max_e m[src_e] : 0) ----------------
// one wave per node; lane holds 2 cols (float2). Optional fused relu.
__global__ __launch_bounds__(256) void agg_kernel(const float* __restrict__ m,
                                                  const int* __restrict__ offs,
                                                  const int* __restrict__ esrc,
                                                  const float* __restrict__ base,
                                                  float* __restrict__ out, int do_relu) {
    int wv = threadIdx.x >> 6;
    int lane = threadIdx.x & 63;
    int node = blockIdx.x * 4 + wv;
    if (node >= NN) return;
    int beg = offs[node], end = offs[node + 1];
    float ax = -3.402823466e38f, ay = -3.402823466e38f;
    for (int e = beg; e < end; e++) {
        int s = esrc[e];
        float2 v = ((const float2*)(m + (size_t)s * D))[lane];
        ax = fmaxf(ax, v.x);
        ay = fmaxf(ay, v.y);
    }
    float2 b = ((const float2*)(base + (size_t)node * D))[lane];
    float rx = b.x, ry = b.y;
    if (end > beg) { rx += ax; ry += ay; }
    if (do_relu) { rx = fmaxf(rx, 0.f); ry = fmaxf(ry, 0.f); }
    ((float2*)(out + (size_t)node * D))[lane] = make_float2(rx, ry);
}

// ---------------- global add pool (batch is sorted) ----------------
#define PCH 256
__global__ __launch_bounds__(128) void pool_kernel(const float* __restrict__ h,
                                                   const int* __restrict__ batch,
                                                   float* __restrict__ out) {
    int c = threadIdx.x;  // 0..127 one column each
    int n0 = blockIdx.x * PCH;
    if (n0 >= NN) return;
    int n1 = n0 + PCH; if (n1 > NN) n1 = NN;
    int cur = batch[n0];
    float acc = 0.f;
    for (int n = n0; n < n1; n++) {
        int g = batch[n];
        if (g != cur) {
            atomicAdd(&out[cur * D + c], acc);
            acc = 0.f;
            cur = g;
        }
        acc += h[(size_t)n * D + c];
    }
    atomicAdd(&out[cur * D + c], acc);
}

extern "C" void kernel_launch(void* const* d_in, const int* in_sizes, int n_in,
                              void* d_out, int out_size, void* d_ws, size_t ws_size,
                              hipStream_t stream) {
    const float* x = (const float*)d_in[0];
    const int* ei[4] = {(const int*)d_in[1], (const int*)d_in[2],
                        (const int*)d_in[3], (const int*)d_in[4]};
    const int* batch = (const int*)d_in[5];
    const float* emb_w = (const float*)d_in[6];
    const float* emb_b = (const float*)d_in[7];
    const float* root_w = (const float*)d_in[8];
    const float* root_b = (const float*)d_in[9];
    const float* conv_w = (const float*)d_in[10];
    float* out = (float*)d_out;

    // workspace layout
    float* h = (float*)d_ws;                       // NN*D
    float* mbuf = h + (size_t)NN * D;              // NN*D
    float* outb = mbuf + (size_t)NN * D;           // NN*D
    int* offs = (int*)(outb + (size_t)NN * D);     // NR*(NN+1)
    int* counts = offs + (size_t)NR * (NN + 1);    // NR*NN  (counts -> cursor)
    int* esrc = counts + (size_t)NR * NN;          // NR*NE

    // ---- CSR build (edge structure reused across all 4 layers) ----
    zero_i32<<<(NR * NN + 255) / 256, 256, 0, stream>>>(counts, NR * NN);
    for (int r = 0; r < NR; r++)
        count_kernel<<<(NE + 255) / 256, 256, 0, stream>>>(ei[r] + NE, counts + (size_t)r * NN);
    scan_kernel<<<NR, 1024, 0, stream>>>(counts, offs);
    for (int r = 0; r < NR; r++)
        fill_kernel<<<(NE + 255) / 256, 256, 0, stream>>>(ei[r], ei[r] + NE,
                                                          counts + (size_t)r * NN,
                                                          esrc + (size_t)r * NE);

    // ---- embedding: h = x @ emb_w + emb_b ----
    gemm_kernel<FIN><<<1024, 256, 0, stream>>>(x, emb_w, emb_b, h);

    // ---- layers ----
    for (int l = 0; l < NL; l++) {
        gemm_kernel<D><<<1024, 256, 0, stream>>>(h, root_w + (size_t)l * D * D,
                                                 root_b + (size_t)l * D, outb);
        for (int r = 0; r < NR; r++) {
            gemm_kernel<D><<<1024, 256, 0, stream>>>(h, conv_w + (size_t)(l * NR + r) * D * D,
                                                     nullptr, mbuf);
            // r<3: accumulate into outb; r==3: fused relu, write into h (next layer input)
            agg_kernel<<<(NN + 3) / 4, 256, 0, stream>>>(mbuf, offs + (size_t)r * (NN + 1),
                                                         esrc + (size_t)r * NE, outb,
                                                         (r == 3) ? h : outb, (r == 3) ? 1 : 0);
        }
    }

    // ---- global add pool ----
    zero_f32<<<(NGR * D + 255) / 256, 256, 0, stream>>>(out, NGR * D);
    pool_kernel<<<(NN + PCH - 1) / PCH, 128, 0, stream>>>(h, batch, out);
}

// Round 2
// 2354.666 us; speedup vs baseline: 1.2706x; 1.2706x over previous
//
#include <hip/hip_runtime.h>

#define NN 100000   // nodes
#define NE 500000   // edges per relation
#define NR 4        // relations
#define NL 4        // layers
#define FIN 64      // input features
#define D 128       // embedding dim
#define NGR 64      // graphs

#define SCH 1024                      // counts per scan block
#define SBLK ((NN + SCH - 1) / SCH)   // 98 blocks per relation

// ---------------- utility ----------------
__global__ void zero_i32(int* __restrict__ p, int n) {
    int i = blockIdx.x * blockDim.x + threadIdx.x;
    if (i < n) p[i] = 0;
}
__global__ void zero_f32(float* __restrict__ p, int n) {
    int i = blockIdx.x * blockDim.x + threadIdx.x;
    if (i < n) p[i] = 0.f;
}

// ---------------- CSR build (dst-indexed), once per launch ----------------
__global__ void count_kernel(const int* __restrict__ dst, int* __restrict__ cnt) {
    int e = blockIdx.x * blockDim.x + threadIdx.x;
    if (e < NE) atomicAdd(&cnt[dst[e]], 1);
}

// phase 1: per-block sums. grid = NR*SBLK x 256
__global__ __launch_bounds__(256) void scan1(const int* __restrict__ counts,
                                             int* __restrict__ partial) {
    int r = blockIdx.x / SBLK, b = blockIdx.x % SBLK;
    const int* cnt = counts + (size_t)r * NN + (size_t)b * SCH;
    int n = NN - b * SCH; if (n > SCH) n = SCH;
    int t = threadIdx.x;
    int s = 0;
    for (int i = t; i < n; i += 256) s += cnt[i];
    __shared__ int sd[256];
    sd[t] = s; __syncthreads();
    for (int d = 128; d; d >>= 1) { if (t < d) sd[t] += sd[t + d]; __syncthreads(); }
    if (t == 0) partial[r * SBLK + b] = sd[0];
}

// phase 2: exclusive scan of the SBLK partials per relation. grid = NR x 128
__global__ __launch_bounds__(128) void scan2(int* __restrict__ partial, int* __restrict__ offs) {
    int r = blockIdx.x;
    int* p = partial + r * SBLK;
    int t = threadIdx.x;
    __shared__ int sd[128];
    int v = (t < SBLK) ? p[t] : 0;
    sd[t] = v; __syncthreads();
    for (int d = 1; d < 128; d <<= 1) {
        int u = (t >= d) ? sd[t - d] : 0;
        __syncthreads();
        sd[t] += u;
        __syncthreads();
    }
    if (t < SBLK) p[t] = sd[t] - v;  // exclusive
    if (t == 0) offs[(size_t)r * (NN + 1) + NN] = NE;
}

// phase 3: per-block local exclusive scan + base; writes offs and leaves
// counts[] rewritten in place as the fill cursor. grid = NR*SBLK x 256
__global__ __launch_bounds__(256) void scan3(int* __restrict__ counts,
                                             const int* __restrict__ partial,
                                             int* __restrict__ offs) {
    int r = blockIdx.x / SBLK, b = blockIdx.x % SBLK;
    int t = threadIdx.x;
    int* cnt = counts + (size_t)r * NN;
    int* off = offs + (size_t)r * (NN + 1);
    int i0 = b * SCH + t * 4;
    int c[4];
#pragma unroll
    for (int j = 0; j < 4; j++) c[j] = (i0 + j < NN) ? cnt[i0 + j] : 0;
    int ts = c[0] + c[1] + c[2] + c[3];
    __shared__ int sd[256];
    sd[t] = ts; __syncthreads();
    for (int d = 1; d < 256; d <<= 1) {
        int u = (t >= d) ? sd[t - d] : 0;
        __syncthreads();
        sd[t] += u;
        __syncthreads();
    }
    int run = partial[r * SBLK + b] + sd[t] - ts;
#pragma unroll
    for (int j = 0; j < 4; j++) {
        if (i0 + j < NN) {
            off[i0 + j] = run;
            cnt[i0 + j] = run;  // cursor for fill
            run += c[j];
        }
    }
}

__global__ void fill_kernel(const int* __restrict__ src, const int* __restrict__ dst,
                            int* __restrict__ cur, int* __restrict__ esrc) {
    int e = blockIdx.x * blockDim.x + threadIdx.x;
    if (e < NE) {
        int pos = atomicAdd(&cur[dst[e]], 1);
        esrc[pos] = src[e];
    }
}

// ---------------- GEMM: out[n,c] = A[n,:K] @ W[K,128] (+ bias) ----------------
template <int K>
__global__ __launch_bounds__(256) void gemm_kernel(const float* __restrict__ A,
                                                   const float* __restrict__ W,
                                                   const float* __restrict__ bias,
                                                   float* __restrict__ out) {
    __shared__ float Ws[K * D];
    const int tid = threadIdx.x;
    for (int i = tid; i < K * D / 4; i += 256)
        ((float4*)Ws)[i] = ((const float4*)W)[i];
    const int cg = tid & 31;
    const int ng = tid >> 5;
    float bv[4] = {0.f, 0.f, 0.f, 0.f};
    if (bias) {
        float4 b4 = ((const float4*)bias)[cg];
        bv[0] = b4.x; bv[1] = b4.y; bv[2] = b4.z; bv[3] = b4.w;
    }
    __syncthreads();
    for (int tile = blockIdx.x; tile < NN / 32; tile += gridDim.x) {
        const int node0 = tile * 32 + ng * 4;
        const float4* A0 = (const float4*)(A + (size_t)node0 * K);
        float acc[4][4];
#pragma unroll
        for (int j = 0; j < 4; j++)
#pragma unroll
            for (int c = 0; c < 4; c++) acc[j][c] = bv[c];
#pragma unroll 4
        for (int k4 = 0; k4 < K / 4; k4++) {
            float a[4][4], w[4][4];
            *(float4*)a[0] = A0[0 * (K / 4) + k4];
            *(float4*)a[1] = A0[1 * (K / 4) + k4];
            *(float4*)a[2] = A0[2 * (K / 4) + k4];
            *(float4*)a[3] = A0[3 * (K / 4) + k4];
            *(float4*)w[0] = *(const float4*)&Ws[(k4 * 4 + 0) * D + cg * 4];
            *(float4*)w[1] = *(const float4*)&Ws[(k4 * 4 + 1) * D + cg * 4];
            *(float4*)w[2] = *(const float4*)&Ws[(k4 * 4 + 2) * D + cg * 4];
            *(float4*)w[3] = *(const float4*)&Ws[(k4 * 4 + 3) * D + cg * 4];
#pragma unroll
            for (int kk = 0; kk < 4; kk++)
#pragma unroll
                for (int j = 0; j < 4; j++)
#pragma unroll
                    for (int c = 0; c < 4; c++) acc[j][c] += a[j][kk] * w[kk][c];
        }
#pragma unroll
        for (int j = 0; j < 4; j++) {
            float4 o = make_float4(acc[j][0], acc[j][1], acc[j][2], acc[j][3]);
            ((float4*)(out + (size_t)(node0 + j) * D))[cg] = o;
        }
    }
}

// ---------------- fused multi-relation scatter-max aggregation ----------------
// one wave per node; lane holds 2 cols. Edge indices for up to 64 edges are
// loaded with ONE coalesced load and broadcast via shfl; gathers are unrolled
// 4-wide into 4 independent accumulators for memory-level parallelism.
#define NINF -3.402823466e38f
__global__ __launch_bounds__(256) void agg_kernel(const float* __restrict__ mb,
                                                  const int* __restrict__ offs,
                                                  const int* __restrict__ esrc,
                                                  int G,
                                                  const float* __restrict__ base,
                                                  float* __restrict__ out, int do_relu) {
    int wv = threadIdx.x >> 6;
    int lane = threadIdx.x & 63;
    int node = blockIdx.x * 4 + wv;
    if (node >= NN) return;
    float2 b = ((const float2*)(base + (size_t)node * D))[lane];
    float rx = b.x, ry = b.y;
    for (int g = 0; g < G; g++) {
        const int* off = offs + (size_t)g * (NN + 1);
        const float* m = mb + (size_t)g * NN * D;
        const int* es = esrc + (size_t)g * NE;
        int beg = off[node], end = off[node + 1];
        int nd = end - beg;
        if (nd <= 0) continue;
        float a0x = NINF, a0y = NINF, a1x = NINF, a1y = NINF;
        float a2x = NINF, a2y = NINF, a3x = NINF, a3y = NINF;
        for (int c0 = 0; c0 < nd; c0 += 64) {
            int cnt = nd - c0; if (cnt > 64) cnt = 64;
            int s_l = (lane < cnt) ? es[beg + c0 + lane] : 0;
            int i = 0;
            for (; i + 4 <= cnt; i += 4) {
                int s0 = __shfl(s_l, i + 0);
                int s1 = __shfl(s_l, i + 1);
                int s2 = __shfl(s_l, i + 2);
                int s3 = __shfl(s_l, i + 3);
                float2 v0 = ((const float2*)(m + (size_t)s0 * D))[lane];
                float2 v1 = ((const float2*)(m + (size_t)s1 * D))[lane];
                float2 v2 = ((const float2*)(m + (size_t)s2 * D))[lane];
                float2 v3 = ((const float2*)(m + (size_t)s3 * D))[lane];
                a0x = fmaxf(a0x, v0.x); a0y = fmaxf(a0y, v0.y);
                a1x = fmaxf(a1x, v1.x); a1y = fmaxf(a1y, v1.y);
                a2x = fmaxf(a2x, v2.x); a2y = fmaxf(a2y, v2.y);
                a3x = fmaxf(a3x, v3.x); a3y = fmaxf(a3y, v3.y);
            }
            for (; i < cnt; i++) {
                int s = __shfl(s_l, i);
                float2 v = ((const float2*)(m + (size_t)s * D))[lane];
                a0x = fmaxf(a0x, v.x); a0y = fmaxf(a0y, v.y);
            }
        }
        rx += fmaxf(fmaxf(a0x, a1x), fmaxf(a2x, a3x));
        ry += fmaxf(fmaxf(a0y, a1y), fmaxf(a2y, a3y));
    }
    if (do_relu) { rx = fmaxf(rx, 0.f); ry = fmaxf(ry, 0.f); }
    ((float2*)(out + (size_t)node * D))[lane] = make_float2(rx, ry);
}

// ---------------- global add pool (batch is sorted) ----------------
#define PCH 256
__global__ __launch_bounds__(128) void pool_kernel(const float* __restrict__ h,
                                                   const int* __restrict__ batch,
                                                   float* __restrict__ out) {
    int c = threadIdx.x;
    int n0 = blockIdx.x * PCH;
    if (n0 >= NN) return;
    int n1 = n0 + PCH; if (n1 > NN) n1 = NN;
    int cur = batch[n0];
    float acc = 0.f;
    for (int n = n0; n < n1; n++) {
        int g = batch[n];
        if (g != cur) {
            atomicAdd(&out[cur * D + c], acc);
            acc = 0.f;
            cur = g;
        }
        acc += h[(size_t)n * D + c];
    }
    atomicAdd(&out[cur * D + c], acc);
}

extern "C" void kernel_launch(void* const* d_in, const int* in_sizes, int n_in,
                              void* d_out, int out_size, void* d_ws, size_t ws_size,
                              hipStream_t stream) {
    const float* x = (const float*)d_in[0];
    const int* ei[4] = {(const int*)d_in[1], (const int*)d_in[2],
                        (const int*)d_in[3], (const int*)d_in[4]};
    const int* batch = (const int*)d_in[5];
    const float* emb_w = (const float*)d_in[6];
    const float* emb_b = (const float*)d_in[7];
    const float* root_w = (const float*)d_in[8];
    const float* root_b = (const float*)d_in[9];
    const float* conv_w = (const float*)d_in[10];
    float* out = (float*)d_out;

    // pick relation-group size G by workspace capacity (ws_size is constant
    // across calls, so this branch does the same work every launch)
    const size_t intBytes = ((size_t)NR * (NN + 1) + (size_t)NR * NN + (size_t)NR * NE
                             + NR * SBLK) * 4;
    int G = 1;
    if (ws_size >= (size_t)NN * D * 4 * (2 + 4) + intBytes) G = 4;
    else if (ws_size >= (size_t)NN * D * 4 * (2 + 2) + intBytes) G = 2;

    // workspace layout
    float* h = (float*)d_ws;                        // NN*D
    float* outb = h + (size_t)NN * D;               // NN*D
    float* mbuf = outb + (size_t)NN * D;            // G*NN*D
    int* offs = (int*)(mbuf + (size_t)G * NN * D);  // NR*(NN+1)
    int* counts = offs + (size_t)NR * (NN + 1);     // NR*NN (-> cursor)
    int* esrc = counts + (size_t)NR * NN;           // NR*NE
    int* partial = esrc + (size_t)NR * NE;          // NR*SBLK

    // ---- CSR build (edge structure reused across all layers) ----
    zero_i32<<<(NR * NN + 255) / 256, 256, 0, stream>>>(counts, NR * NN);
    for (int r = 0; r < NR; r++)
        count_kernel<<<(NE + 255) / 256, 256, 0, stream>>>(ei[r] + NE, counts + (size_t)r * NN);
    scan1<<<NR * SBLK, 256, 0, stream>>>(counts, partial);
    scan2<<<NR, 128, 0, stream>>>(partial, offs);
    scan3<<<NR * SBLK, 256, 0, stream>>>(counts, partial, offs);
    for (int r = 0; r < NR; r++)
        fill_kernel<<<(NE + 255) / 256, 256, 0, stream>>>(ei[r], ei[r] + NE,
                                                          counts + (size_t)r * NN,
                                                          esrc + (size_t)r * NE);

    // ---- embedding ----
    gemm_kernel<FIN><<<1024, 256, 0, stream>>>(x, emb_w, emb_b, h);

    // ---- layers ----
    for (int l = 0; l < NL; l++) {
        gemm_kernel<D><<<1024, 256, 0, stream>>>(h, root_w + (size_t)l * D * D,
                                                 root_b + (size_t)l * D, outb);
        for (int g0 = 0; g0 < NR; g0 += G) {
            for (int r = g0; r < g0 + G; r++)
                gemm_kernel<D><<<1024, 256, 0, stream>>>(
                    h, conv_w + (size_t)(l * NR + r) * D * D, nullptr,
                    mbuf + (size_t)(r - g0) * NN * D);
            int last = (g0 + G == NR);
            agg_kernel<<<(NN + 3) / 4, 256, 0, stream>>>(
                mbuf, offs + (size_t)g0 * (NN + 1), esrc + (size_t)g0 * NE, G,
                outb, last ? h : outb, last ? 1 : 0);
        }
    }

    // ---- global add pool ----
    zero_f32<<<(NGR * D + 255) / 256, 256, 0, stream>>>(out, NGR * D);
    pool_kernel<<<(NN + PCH - 1) / PCH, 128, 0, stream>>>(h, batch, out);
}

// Round 3
// 1374.655 us; speedup vs baseline: 2.1765x; 1.7129x over previous
//
#include <hip/hip_runtime.h>

#define NN 100000   // nodes
#define NE 500000   // edges per relation
#define NR 4        // relations
#define NL 4        // layers
#define FIN 64      // input features
#define D 128       // embedding dim
#define NGR 64      // graphs

#define SCH 1024
#define SBLK ((NN + SCH - 1) / SCH)   // 98

typedef __attribute__((ext_vector_type(8))) short short8;
typedef __attribute__((ext_vector_type(4))) float f32x4;
typedef unsigned short ushort;
typedef unsigned int uint;

__device__ __forceinline__ ushort f2b(float f) {
    uint u = __float_as_uint(f);
    uint r = (u + 0x7fffu + ((u >> 16) & 1u)) >> 16;  // RNE
    return (ushort)r;
}
__device__ __forceinline__ float b2f(ushort b) {
    return __uint_as_float(((uint)b) << 16);
}

// ---------------- utility ----------------
__global__ void zero_i32(int* __restrict__ p, int n) {
    int i = blockIdx.x * blockDim.x + threadIdx.x;
    if (i < n) p[i] = 0;
}
__global__ void zero_f32(float* __restrict__ p, int n) {
    int i = blockIdx.x * blockDim.x + threadIdx.x;
    if (i < n) p[i] = 0.f;
}
__global__ void xcvt(const float* __restrict__ x, ushort* __restrict__ xb, int n) {
    int i = blockIdx.x * blockDim.x + threadIdx.x;
    if (i < n) xb[i] = f2b(x[i]);
}

// W fp32 [nmat][K x 128] -> bf16 MFMA B-fragment order:
// dst[(((t*(K/32)+k0)*64 + lane)*8 + j)] = W[k0*32 + (lane>>4)*8 + j][t*16 + (lane&15)]
__global__ void wperm_kernel(const float* __restrict__ W, ushort* __restrict__ dst,
                             int K, int total) {
    int i = blockIdx.x * blockDim.x + threadIdx.x;
    if (i >= total) return;
    int per = K * 128;
    int mi = i / per;
    int o = i - mi * per;
    int j = o & 7, lane = (o >> 3) & 63, rest = o >> 9;
    int K032 = K / 32;
    int k0 = rest % K032, t = rest / K032;
    int k = k0 * 32 + (lane >> 4) * 8 + j;
    int n = t * 16 + (lane & 15);
    dst[i] = f2b(W[(size_t)mi * per + k * 128 + n]);
}

// ---------------- CSR build ----------------
__global__ void count_kernel(const int* __restrict__ dst, int* __restrict__ cnt) {
    int e = blockIdx.x * blockDim.x + threadIdx.x;
    if (e < NE) atomicAdd(&cnt[dst[e]], 1);
}

__global__ __launch_bounds__(256) void scan1(const int* __restrict__ counts,
                                             int* __restrict__ partial) {
    int r = blockIdx.x / SBLK, b = blockIdx.x % SBLK;
    const int* cnt = counts + (size_t)r * NN + (size_t)b * SCH;
    int n = NN - b * SCH; if (n > SCH) n = SCH;
    int t = threadIdx.x;
    int s = 0;
    for (int i = t; i < n; i += 256) s += cnt[i];
    __shared__ int sd[256];
    sd[t] = s; __syncthreads();
    for (int d = 128; d; d >>= 1) { if (t < d) sd[t] += sd[t + d]; __syncthreads(); }
    if (t == 0) partial[r * SBLK + b] = sd[0];
}

__global__ __launch_bounds__(128) void scan2(int* __restrict__ partial, int* __restrict__ offs) {
    int r = blockIdx.x;
    int* p = partial + r * SBLK;
    int t = threadIdx.x;
    __shared__ int sd[128];
    int v = (t < SBLK) ? p[t] : 0;
    sd[t] = v; __syncthreads();
    for (int d = 1; d < 128; d <<= 1) {
        int u = (t >= d) ? sd[t - d] : 0;
        __syncthreads();
        sd[t] += u;
        __syncthreads();
    }
    if (t < SBLK) p[t] = sd[t] - v;
    if (t == 0) offs[(size_t)r * (NN + 1) + NN] = NE;
}

__global__ __launch_bounds__(256) void scan3(int* __restrict__ counts,
                                             const int* __restrict__ partial,
                                             int* __restrict__ offs) {
    int r = blockIdx.x / SBLK, b = blockIdx.x % SBLK;
    int t = threadIdx.x;
    int* cnt = counts + (size_t)r * NN;
    int* off = offs + (size_t)r * (NN + 1);
    int i0 = b * SCH + t * 4;
    int c[4];
#pragma unroll
    for (int j = 0; j < 4; j++) c[j] = (i0 + j < NN) ? cnt[i0 + j] : 0;
    int ts = c[0] + c[1] + c[2] + c[3];
    __shared__ int sd[256];
    sd[t] = ts; __syncthreads();
    for (int d = 1; d < 256; d <<= 1) {
        int u = (t >= d) ? sd[t - d] : 0;
        __syncthreads();
        sd[t] += u;
        __syncthreads();
    }
    int run = partial[r * SBLK + b] + sd[t] - ts;
#pragma unroll
    for (int j = 0; j < 4; j++) {
        if (i0 + j < NN) {
            off[i0 + j] = run;
            cnt[i0 + j] = run;
            run += c[j];
        }
    }
}

__global__ void fill_kernel(const int* __restrict__ src, const int* __restrict__ dst,
                            int* __restrict__ cur, int* __restrict__ esrc) {
    int e = blockIdx.x * blockDim.x + threadIdx.x;
    if (e < NE) {
        int pos = atomicAdd(&cur[dst[e]], 1);
        esrc[pos] = src[e];
    }
}

// ---------------- bf16 MFMA GEMM: C[n,:] = A[n,:K](bf16) @ W(K x 128, pre-permuted) ----------------
// 256 thr = 4 waves. wave: ch=w&1 -> cols ch*64..+63 (4 col-tiles), rg=w>>1 -> 16 rows.
// All 4*K/32 B-frags held in VGPRs (loaded once via LDS); K-loop = pure MFMA + one
// 16B A-load per k0. C/D layout: col=lane&15, row=(lane>>4)*4+reg (verified).
template <int K, bool OBF16>
__global__ __launch_bounds__(256) void mgemm(const ushort* __restrict__ A,
                                             const ushort* __restrict__ Bp,
                                             const float* __restrict__ bias,
                                             float* __restrict__ Cf,
                                             ushort* __restrict__ Ch) {
    constexpr int K032 = K / 32;
    __shared__ ushort Bs[8 * K032 * 64 * 8];
    const int tid = threadIdx.x;
    for (int i = tid; i < K * 16; i += 256)
        ((float4*)Bs)[i] = ((const float4*)Bp)[i];
    const int lane = tid & 63, wave = tid >> 6;
    const int quad = lane >> 4, l15 = lane & 15;
    const int ch = wave & 1, rg = wave >> 1;
    __syncthreads();
    short8 breg[4][K032];
#pragma unroll
    for (int tt = 0; tt < 4; tt++)
#pragma unroll
        for (int k0 = 0; k0 < K032; k0++)
            breg[tt][k0] = *(const short8*)&Bs[(size_t)(((ch * 4 + tt) * K032 + k0) * 64 + lane) * 8];
    float bv[4] = {0.f, 0.f, 0.f, 0.f};
    if (bias)
#pragma unroll
        for (int tt = 0; tt < 4; tt++) bv[tt] = bias[(ch * 4 + tt) * 16 + l15];
    for (int tile = blockIdx.x; tile < NN / 32; tile += gridDim.x) {
        const int row0 = tile * 32 + rg * 16;
        const ushort* Ar = A + (size_t)(row0 + l15) * K + quad * 8;
        short8 a[K032];
#pragma unroll
        for (int k0 = 0; k0 < K032; k0++) a[k0] = *(const short8*)(Ar + k0 * 32);
        f32x4 acc[4];
#pragma unroll
        for (int tt = 0; tt < 4; tt++) acc[tt] = (f32x4){bv[tt], bv[tt], bv[tt], bv[tt]};
#pragma unroll
        for (int k0 = 0; k0 < K032; k0++)
#pragma unroll
            for (int tt = 0; tt < 4; tt++)
                acc[tt] = __builtin_amdgcn_mfma_f32_16x16x32_bf16(a[k0], breg[tt][k0], acc[tt], 0, 0, 0);
#pragma unroll
        for (int tt = 0; tt < 4; tt++) {
            const int col = (ch * 4 + tt) * 16 + l15;
#pragma unroll
            for (int r = 0; r < 4; r++) {
                size_t idx = (size_t)(row0 + quad * 4 + r) * D + col;
                if (OBF16) Ch[idx] = f2b(acc[tt][r]);
                else Cf[idx] = acc[tt][r];
            }
        }
    }
}

// ---------------- fused multi-relation scatter-max ----------------
#define NINF -3.402823466e38f
__global__ __launch_bounds__(256) void agg_kernel(const float* __restrict__ mb,
                                                  const int* __restrict__ offs,
                                                  const int* __restrict__ esrc,
                                                  int G,
                                                  const float* __restrict__ base,
                                                  float* __restrict__ outf,
                                                  ushort* __restrict__ outh,
                                                  int mode) {  // 0: fp32 out, 1: relu+bf16 out
    int wv = threadIdx.x >> 6;
    int lane = threadIdx.x & 63;
    int node = blockIdx.x * 4 + wv;
    if (node >= NN) return;
    float2 b = ((const float2*)(base + (size_t)node * D))[lane];
    float rx = b.x, ry = b.y;
    for (int g = 0; g < G; g++) {
        const int* off = offs + (size_t)g * (NN + 1);
        const float* m = mb + (size_t)g * NN * D;
        const int* es = esrc + (size_t)g * NE;
        int beg = off[node], end = off[node + 1];
        int nd = end - beg;
        if (nd <= 0) continue;
        float a0x = NINF, a0y = NINF, a1x = NINF, a1y = NINF;
        float a2x = NINF, a2y = NINF, a3x = NINF, a3y = NINF;
        for (int c0 = 0; c0 < nd; c0 += 64) {
            int cnt = nd - c0; if (cnt > 64) cnt = 64;
            int s_l = (lane < cnt) ? es[beg + c0 + lane] : 0;
            int i = 0;
            for (; i + 4 <= cnt; i += 4) {
                int s0 = __shfl(s_l, i + 0);
                int s1 = __shfl(s_l, i + 1);
                int s2 = __shfl(s_l, i + 2);
                int s3 = __shfl(s_l, i + 3);
                float2 v0 = ((const float2*)(m + (size_t)s0 * D))[lane];
                float2 v1 = ((const float2*)(m + (size_t)s1 * D))[lane];
                float2 v2 = ((const float2*)(m + (size_t)s2 * D))[lane];
                float2 v3 = ((const float2*)(m + (size_t)s3 * D))[lane];
                a0x = fmaxf(a0x, v0.x); a0y = fmaxf(a0y, v0.y);
                a1x = fmaxf(a1x, v1.x); a1y = fmaxf(a1y, v1.y);
                a2x = fmaxf(a2x, v2.x); a2y = fmaxf(a2y, v2.y);
                a3x = fmaxf(a3x, v3.x); a3y = fmaxf(a3y, v3.y);
            }
            for (; i < cnt; i++) {
                int s = __shfl(s_l, i);
                float2 v = ((const float2*)(m + (size_t)s * D))[lane];
                a0x = fmaxf(a0x, v.x); a0y = fmaxf(a0y, v.y);
            }
        }
        rx += fmaxf(fmaxf(a0x, a1x), fmaxf(a2x, a3x));
        ry += fmaxf(fmaxf(a0y, a1y), fmaxf(a2y, a3y));
    }
    if (mode) {
        rx = fmaxf(rx, 0.f); ry = fmaxf(ry, 0.f);
        uint pk = (uint)f2b(rx) | ((uint)f2b(ry) << 16);
        ((uint*)(outh + (size_t)node * D))[lane] = pk;
    } else {
        ((float2*)(outf + (size_t)node * D))[lane] = make_float2(rx, ry);
    }
}

// ---------------- global add pool (batch sorted), h in bf16 ----------------
#define PCH 256
__global__ __launch_bounds__(128) void pool_kernel(const ushort* __restrict__ h,
                                                   const int* __restrict__ batch,
                                                   float* __restrict__ out) {
    int c = threadIdx.x;
    int n0 = blockIdx.x * PCH;
    if (n0 >= NN) return;
    int n1 = n0 + PCH; if (n1 > NN) n1 = NN;
    int cur = batch[n0];
    float acc = 0.f;
    for (int n = n0; n < n1; n++) {
        int g = batch[n];
        if (g != cur) {
            atomicAdd(&out[cur * D + c], acc);
            acc = 0.f;
            cur = g;
        }
        acc += b2f(h[(size_t)n * D + c]);
    }
    atomicAdd(&out[cur * D + c], acc);
}

extern "C" void kernel_launch(void* const* d_in, const int* in_sizes, int n_in,
                              void* d_out, int out_size, void* d_ws, size_t ws_size,
                              hipStream_t stream) {
    const float* x = (const float*)d_in[0];
    const int* ei[4] = {(const int*)d_in[1], (const int*)d_in[2],
                        (const int*)d_in[3], (const int*)d_in[4]};
    const int* batch = (const int*)d_in[5];
    const float* emb_w = (const float*)d_in[6];
    const float* emb_b = (const float*)d_in[7];
    const float* root_w = (const float*)d_in[8];
    const float* root_b = (const float*)d_in[9];
    const float* conv_w = (const float*)d_in[10];
    float* out = (float*)d_out;

    const size_t WPT = (size_t)FIN * 128 + 20 * (size_t)128 * 128;  // permuted weights (ushorts)
    const size_t ushorts = (size_t)NN * D + (size_t)NN * FIN + WPT;
    const size_t ints = (size_t)NR * (NN + 1) + (size_t)NR * NN + (size_t)NR * NE + NR * SBLK;
    // pick relation-group size G (ws_size constant across calls)
    int G = 1;
    for (int g = 4; g >= 2; g >>= 1) {
        size_t need = ((size_t)NN * D * (1 + g)) * 4 + ushorts * 2 + ints * 4;
        if (ws_size >= need) { G = g; break; }
    }

    // workspace layout
    float* outb = (float*)d_ws;                        // NN*D
    float* mbuf = outb + (size_t)NN * D;               // G*NN*D
    ushort* hb = (ushort*)(mbuf + (size_t)G * NN * D); // NN*D
    ushort* xb = hb + (size_t)NN * D;                  // NN*FIN
    ushort* wp = xb + (size_t)NN * FIN;                // WPT
    int* offs = (int*)(wp + WPT);                      // NR*(NN+1)
    int* counts = offs + (size_t)NR * (NN + 1);        // NR*NN (-> cursor)
    int* esrc = counts + (size_t)NR * NN;              // NR*NE
    int* partial = esrc + (size_t)NR * NE;             // NR*SBLK
    ushort* wpEmb = wp;
    ushort* wpRoot = wp + (size_t)FIN * 128;
    ushort* wpConv = wpRoot + (size_t)4 * 128 * 128;

    // ---- CSR build ----
    zero_i32<<<(NR * NN + 255) / 256, 256, 0, stream>>>(counts, NR * NN);
    for (int r = 0; r < NR; r++)
        count_kernel<<<(NE + 255) / 256, 256, 0, stream>>>(ei[r] + NE, counts + (size_t)r * NN);
    scan1<<<NR * SBLK, 256, 0, stream>>>(counts, partial);
    scan2<<<NR, 128, 0, stream>>>(partial, offs);
    scan3<<<NR * SBLK, 256, 0, stream>>>(counts, partial, offs);
    for (int r = 0; r < NR; r++)
        fill_kernel<<<(NE + 255) / 256, 256, 0, stream>>>(ei[r], ei[r] + NE,
                                                          counts + (size_t)r * NN,
                                                          esrc + (size_t)r * NE);

    // ---- weight permute + input convert ----
    {
        int t1 = FIN * 128;
        wperm_kernel<<<(t1 + 255) / 256, 256, 0, stream>>>(emb_w, wpEmb, FIN, t1);
        int t2 = 4 * 128 * 128;
        wperm_kernel<<<(t2 + 255) / 256, 256, 0, stream>>>(root_w, wpRoot, 128, t2);
        int t3 = 16 * 128 * 128;
        wperm_kernel<<<(t3 + 255) / 256, 256, 0, stream>>>(conv_w, wpConv, 128, t3);
        int t4 = NN * FIN;
        xcvt<<<(t4 + 255) / 256, 256, 0, stream>>>(x, xb, t4);
    }

    // ---- embedding: hb = bf16(x @ emb_w + emb_b) ----
    mgemm<FIN, true><<<1024, 256, 0, stream>>>(xb, wpEmb, emb_b, nullptr, hb);

    // ---- layers ----
    for (int l = 0; l < NL; l++) {
        mgemm<128, false><<<1024, 256, 0, stream>>>(hb, wpRoot + (size_t)l * 128 * 128,
                                                    root_b + (size_t)l * D, outb, nullptr);
        for (int g0 = 0; g0 < NR; g0 += G) {
            for (int r = g0; r < g0 + G; r++)
                mgemm<128, false><<<1024, 256, 0, stream>>>(
                    hb, wpConv + (size_t)(l * NR + r) * 128 * 128, nullptr,
                    mbuf + (size_t)(r - g0) * NN * D, nullptr);
            int last = (g0 + G == NR);
            agg_kernel<<<(NN + 3) / 4, 256, 0, stream>>>(
                mbuf, offs + (size_t)g0 * (NN + 1), esrc + (size_t)g0 * NE, G,
                outb, outb, hb, last ? 1 : 0);
        }
    }

    // ---- global add pool ----
    zero_f32<<<(NGR * D + 255) / 256, 256, 0, stream>>>(out, NGR * D);
    pool_kernel<<<(NN + PCH - 1) / PCH, 128, 0, stream>>>(hb, batch, out);
}

// Round 4
// 1117.605 us; speedup vs baseline: 2.6771x; 1.2300x over previous
//
#include <hip/hip_runtime.h>

#define NN 100000   // nodes
#define NE 500000   // edges per relation
#define NR 4        // relations
#define NL 4        // layers
#define FIN 64      // input features
#define D 128       // embedding dim
#define NGR 64      // graphs

#define SCH 1024
#define SBLK ((NN + SCH - 1) / SCH)   // 98

typedef __attribute__((ext_vector_type(8))) short short8;
typedef __attribute__((ext_vector_type(4))) float f32x4;
typedef unsigned short ushort;
typedef unsigned int uint;

__device__ __forceinline__ ushort f2b(float f) {
    uint u = __float_as_uint(f);
    uint r = (u + 0x7fffu + ((u >> 16) & 1u)) >> 16;  // RNE
    return (ushort)r;
}
__device__ __forceinline__ float b2f(ushort b) {
    return __uint_as_float(((uint)b) << 16);
}
__device__ __forceinline__ float blo(uint p) { return __uint_as_float(p << 16); }
__device__ __forceinline__ float bhi(uint p) { return __uint_as_float(p & 0xffff0000u); }

// ---------------- utility ----------------
__global__ void zero_i32(int* __restrict__ p, int n) {
    int i = blockIdx.x * blockDim.x + threadIdx.x;
    if (i < n) p[i] = 0;
}
__global__ void zero_f32(float* __restrict__ p, int n) {
    int i = blockIdx.x * blockDim.x + threadIdx.x;
    if (i < n) p[i] = 0.f;
}
__global__ void xcvt(const float* __restrict__ x, ushort* __restrict__ xb, int n) {
    int i = blockIdx.x * blockDim.x + threadIdx.x;
    if (i < n) xb[i] = f2b(x[i]);
}

// W fp32 [nmat][K x 128] -> bf16 MFMA B-fragment order
__global__ void wperm_kernel(const float* __restrict__ W, ushort* __restrict__ dst,
                             int K, int total) {
    int i = blockIdx.x * blockDim.x + threadIdx.x;
    if (i >= total) return;
    int per = K * 128;
    int mi = i / per;
    int o = i - mi * per;
    int j = o & 7, lane = (o >> 3) & 63, rest = o >> 9;
    int K032 = K / 32;
    int k0 = rest % K032, t = rest / K032;
    int k = k0 * 32 + (lane >> 4) * 8 + j;
    int n = t * 16 + (lane & 15);
    dst[i] = f2b(W[(size_t)mi * per + k * 128 + n]);
}

// ---------------- CSR build ----------------
__global__ void count_kernel(const int* __restrict__ dst, int* __restrict__ cnt) {
    int e = blockIdx.x * blockDim.x + threadIdx.x;
    if (e < NE) atomicAdd(&cnt[dst[e]], 1);
}

__global__ __launch_bounds__(256) void scan1(const int* __restrict__ counts,
                                             int* __restrict__ partial) {
    int r = blockIdx.x / SBLK, b = blockIdx.x % SBLK;
    const int* cnt = counts + (size_t)r * NN + (size_t)b * SCH;
    int n = NN - b * SCH; if (n > SCH) n = SCH;
    int t = threadIdx.x;
    int s = 0;
    for (int i = t; i < n; i += 256) s += cnt[i];
    __shared__ int sd[256];
    sd[t] = s; __syncthreads();
    for (int d = 128; d; d >>= 1) { if (t < d) sd[t] += sd[t + d]; __syncthreads(); }
    if (t == 0) partial[r * SBLK + b] = sd[0];
}

__global__ __launch_bounds__(128) void scan2(int* __restrict__ partial, int* __restrict__ offs) {
    int r = blockIdx.x;
    int* p = partial + r * SBLK;
    int t = threadIdx.x;
    __shared__ int sd[128];
    int v = (t < SBLK) ? p[t] : 0;
    sd[t] = v; __syncthreads();
    for (int d = 1; d < 128; d <<= 1) {
        int u = (t >= d) ? sd[t - d] : 0;
        __syncthreads();
        sd[t] += u;
        __syncthreads();
    }
    if (t < SBLK) p[t] = sd[t] - v;
    if (t == 0) offs[(size_t)r * (NN + 1) + NN] = NE;
}

__global__ __launch_bounds__(256) void scan3(int* __restrict__ counts,
                                             const int* __restrict__ partial,
                                             int* __restrict__ offs) {
    int r = blockIdx.x / SBLK, b = blockIdx.x % SBLK;
    int t = threadIdx.x;
    int* cnt = counts + (size_t)r * NN;
    int* off = offs + (size_t)r * (NN + 1);
    int i0 = b * SCH + t * 4;
    int c[4];
#pragma unroll
    for (int j = 0; j < 4; j++) c[j] = (i0 + j < NN) ? cnt[i0 + j] : 0;
    int ts = c[0] + c[1] + c[2] + c[3];
    __shared__ int sd[256];
    sd[t] = ts; __syncthreads();
    for (int d = 1; d < 256; d <<= 1) {
        int u = (t >= d) ? sd[t - d] : 0;
        __syncthreads();
        sd[t] += u;
        __syncthreads();
    }
    int run = partial[r * SBLK + b] + sd[t] - ts;
#pragma unroll
    for (int j = 0; j < 4; j++) {
        if (i0 + j < NN) {
            off[i0 + j] = run;
            cnt[i0 + j] = run;
            run += c[j];
        }
    }
}

__global__ void fill_kernel(const int* __restrict__ src, const int* __restrict__ dst,
                            int* __restrict__ cur, int* __restrict__ esrc) {
    int e = blockIdx.x * blockDim.x + threadIdx.x;
    if (e < NE) {
        int pos = atomicAdd(&cur[dst[e]], 1);
        esrc[pos] = src[e];
    }
}

// ---------------- bf16 MFMA GEMM: Ch[n,:] = bf16(A[n,:K] @ W + bias) ----------------
template <int K>
__global__ __launch_bounds__(256) void mgemm(const ushort* __restrict__ A,
                                             const ushort* __restrict__ Bp,
                                             const float* __restrict__ bias,
                                             ushort* __restrict__ Ch) {
    constexpr int K032 = K / 32;
    __shared__ ushort Bs[8 * K032 * 64 * 8];
    const int tid = threadIdx.x;
    for (int i = tid; i < K * 16; i += 256)
        ((float4*)Bs)[i] = ((const float4*)Bp)[i];
    const int lane = tid & 63, wave = tid >> 6;
    const int quad = lane >> 4, l15 = lane & 15;
    const int ch = wave & 1, rg = wave >> 1;
    __syncthreads();
    short8 breg[4][K032];
#pragma unroll
    for (int tt = 0; tt < 4; tt++)
#pragma unroll
        for (int k0 = 0; k0 < K032; k0++)
            breg[tt][k0] = *(const short8*)&Bs[(size_t)(((ch * 4 + tt) * K032 + k0) * 64 + lane) * 8];
    float bv[4] = {0.f, 0.f, 0.f, 0.f};
    if (bias)
#pragma unroll
        for (int tt = 0; tt < 4; tt++) bv[tt] = bias[(ch * 4 + tt) * 16 + l15];
    for (int tile = blockIdx.x; tile < NN / 32; tile += gridDim.x) {
        const int row0 = tile * 32 + rg * 16;
        const ushort* Ar = A + (size_t)(row0 + l15) * K + quad * 8;
        short8 a[K032];
#pragma unroll
        for (int k0 = 0; k0 < K032; k0++) a[k0] = *(const short8*)(Ar + k0 * 32);
        f32x4 acc[4];
#pragma unroll
        for (int tt = 0; tt < 4; tt++) acc[tt] = (f32x4){bv[tt], bv[tt], bv[tt], bv[tt]};
#pragma unroll
        for (int k0 = 0; k0 < K032; k0++)
#pragma unroll
            for (int tt = 0; tt < 4; tt++)
                acc[tt] = __builtin_amdgcn_mfma_f32_16x16x32_bf16(a[k0], breg[tt][k0], acc[tt], 0, 0, 0);
#pragma unroll
        for (int tt = 0; tt < 4; tt++) {
            const int col = (ch * 4 + tt) * 16 + l15;
#pragma unroll
            for (int r = 0; r < 4; r++)
                Ch[(size_t)(row0 + quad * 4 + r) * D + col] = f2b(acc[tt][r]);
        }
    }
}

// ---------------- fused multi-relation scatter-max (all bf16 node data) ----------------
#define NINF -3.402823466e38f
__global__ __launch_bounds__(256) void agg_kernel(const ushort* __restrict__ mb,
                                                  const int* __restrict__ offs,
                                                  const int* __restrict__ esrc,
                                                  int G,
                                                  const ushort* __restrict__ base,
                                                  ushort* __restrict__ outh,
                                                  int do_relu) {
    int wv = threadIdx.x >> 6;
    int lane = threadIdx.x & 63;
    int node = blockIdx.x * 4 + wv;
    if (node >= NN) return;
    uint bp = ((const uint*)(base + (size_t)node * D))[lane];
    float rx = blo(bp), ry = bhi(bp);
    for (int g = 0; g < G; g++) {
        const int* off = offs + (size_t)g * (NN + 1);
        const ushort* m = mb + (size_t)g * NN * D;
        const int* es = esrc + (size_t)g * NE;
        int beg = off[node], end = off[node + 1];
        int nd = end - beg;
        if (nd <= 0) continue;
        float a0x = NINF, a0y = NINF, a1x = NINF, a1y = NINF;
        float a2x = NINF, a2y = NINF, a3x = NINF, a3y = NINF;
        for (int c0 = 0; c0 < nd; c0 += 64) {
            int cnt = nd - c0; if (cnt > 64) cnt = 64;
            int s_l = (lane < cnt) ? es[beg + c0 + lane] : 0;
            int i = 0;
            for (; i + 4 <= cnt; i += 4) {
                int s0 = __shfl(s_l, i + 0);
                int s1 = __shfl(s_l, i + 1);
                int s2 = __shfl(s_l, i + 2);
                int s3 = __shfl(s_l, i + 3);
                uint v0 = ((const uint*)(m + (size_t)s0 * D))[lane];
                uint v1 = ((const uint*)(m + (size_t)s1 * D))[lane];
                uint v2 = ((const uint*)(m + (size_t)s2 * D))[lane];
                uint v3 = ((const uint*)(m + (size_t)s3 * D))[lane];
                a0x = fmaxf(a0x, blo(v0)); a0y = fmaxf(a0y, bhi(v0));
                a1x = fmaxf(a1x, blo(v1)); a1y = fmaxf(a1y, bhi(v1));
                a2x = fmaxf(a2x, blo(v2)); a2y = fmaxf(a2y, bhi(v2));
                a3x = fmaxf(a3x, blo(v3)); a3y = fmaxf(a3y, bhi(v3));
            }
            for (; i < cnt; i++) {
                int s = __shfl(s_l, i);
                uint v = ((const uint*)(m + (size_t)s * D))[lane];
                a0x = fmaxf(a0x, blo(v)); a0y = fmaxf(a0y, bhi(v));
            }
        }
        rx += fmaxf(fmaxf(a0x, a1x), fmaxf(a2x, a3x));
        ry += fmaxf(fmaxf(a0y, a1y), fmaxf(a2y, a3y));
    }
    if (do_relu) { rx = fmaxf(rx, 0.f); ry = fmaxf(ry, 0.f); }
    uint pk = (uint)f2b(rx) | ((uint)f2b(ry) << 16);
    ((uint*)(outh + (size_t)node * D))[lane] = pk;
}

// ---------------- global add pool (batch sorted), h in bf16 ----------------
#define PCH 256
__global__ __launch_bounds__(128) void pool_kernel(const ushort* __restrict__ h,
                                                   const int* __restrict__ batch,
                                                   float* __restrict__ out) {
    int c = threadIdx.x;
    int n0 = blockIdx.x * PCH;
    if (n0 >= NN) return;
    int n1 = n0 + PCH; if (n1 > NN) n1 = NN;
    int cur = batch[n0];
    float acc = 0.f;
    for (int n = n0; n < n1; n++) {
        int g = batch[n];
        if (g != cur) {
            atomicAdd(&out[cur * D + c], acc);
            acc = 0.f;
            cur = g;
        }
        acc += b2f(h[(size_t)n * D + c]);
    }
    atomicAdd(&out[cur * D + c], acc);
}

extern "C" void kernel_launch(void* const* d_in, const int* in_sizes, int n_in,
                              void* d_out, int out_size, void* d_ws, size_t ws_size,
                              hipStream_t stream) {
    const float* x = (const float*)d_in[0];
    const int* ei[4] = {(const int*)d_in[1], (const int*)d_in[2],
                        (const int*)d_in[3], (const int*)d_in[4]};
    const int* batch = (const int*)d_in[5];
    const float* emb_w = (const float*)d_in[6];
    const float* emb_b = (const float*)d_in[7];
    const float* root_w = (const float*)d_in[8];
    const float* root_b = (const float*)d_in[9];
    const float* conv_w = (const float*)d_in[10];
    float* out = (float*)d_out;

    const size_t WPT = (size_t)FIN * 128 + 20 * (size_t)128 * 128;  // permuted weights
    const size_t ints = (size_t)NR * (NN + 1) + (size_t)NR * NN + (size_t)NR * NE + NR * SBLK;
    // relation-group size G by ws capacity (ws_size constant across calls)
    int G = 1;
    for (int g = 4; g >= 2; g >>= 1) {
        size_t need = ((size_t)NN * D * (2 + g) + (size_t)NN * FIN + WPT) * 2 + ints * 4;
        if (ws_size >= need) { G = g; break; }
    }

    // workspace layout (all node buffers bf16)
    ushort* hb = (ushort*)d_ws;                        // NN*D
    ushort* ob = hb + (size_t)NN * D;                  // NN*D (base)
    ushort* mbuf = ob + (size_t)NN * D;                // G*NN*D
    ushort* xb = mbuf + (size_t)G * NN * D;            // NN*FIN
    ushort* wp = xb + (size_t)NN * FIN;                // WPT
    int* offs = (int*)(wp + WPT);                      // NR*(NN+1)
    int* counts = offs + (size_t)NR * (NN + 1);        // NR*NN (-> cursor)
    int* esrc = counts + (size_t)NR * NN;              // NR*NE
    int* partial = esrc + (size_t)NR * NE;             // NR*SBLK
    ushort* wpEmb = wp;
    ushort* wpRoot = wp + (size_t)FIN * 128;
    ushort* wpConv = wpRoot + (size_t)4 * 128 * 128;

    // ---- CSR build ----
    zero_i32<<<(NR * NN + 255) / 256, 256, 0, stream>>>(counts, NR * NN);
    for (int r = 0; r < NR; r++)
        count_kernel<<<(NE + 255) / 256, 256, 0, stream>>>(ei[r] + NE, counts + (size_t)r * NN);
    scan1<<<NR * SBLK, 256, 0, stream>>>(counts, partial);
    scan2<<<NR, 128, 0, stream>>>(partial, offs);
    scan3<<<NR * SBLK, 256, 0, stream>>>(counts, partial, offs);
    for (int r = 0; r < NR; r++)
        fill_kernel<<<(NE + 255) / 256, 256, 0, stream>>>(ei[r], ei[r] + NE,
                                                          counts + (size_t)r * NN,
                                                          esrc + (size_t)r * NE);

    // ---- weight permute + input convert ----
    {
        int t1 = FIN * 128;
        wperm_kernel<<<(t1 + 255) / 256, 256, 0, stream>>>(emb_w, wpEmb, FIN, t1);
        int t2 = 4 * 128 * 128;
        wperm_kernel<<<(t2 + 255) / 256, 256, 0, stream>>>(root_w, wpRoot, 128, t2);
        int t3 = 16 * 128 * 128;
        wperm_kernel<<<(t3 + 255) / 256, 256, 0, stream>>>(conv_w, wpConv, 128, t3);
        int t4 = NN * FIN;
        xcvt<<<(t4 + 255) / 256, 256, 0, stream>>>(x, xb, t4);
    }

    // ---- embedding ----
    mgemm<FIN><<<1024, 256, 0, stream>>>(xb, wpEmb, emb_b, hb);

    // ---- layers ----
    for (int l = 0; l < NL; l++) {
        mgemm<128><<<1024, 256, 0, stream>>>(hb, wpRoot + (size_t)l * 128 * 128,
                                             root_b + (size_t)l * D, ob);
        for (int g0 = 0; g0 < NR; g0 += G) {
            for (int r = g0; r < g0 + G; r++)
                mgemm<128><<<1024, 256, 0, stream>>>(
                    hb, wpConv + (size_t)(l * NR + r) * 128 * 128, nullptr,
                    mbuf + (size_t)(r - g0) * NN * D);
            int last = (g0 + G == NR);
            agg_kernel<<<(NN + 3) / 4, 256, 0, stream>>>(
                mbuf, offs + (size_t)g0 * (NN + 1), esrc + (size_t)g0 * NE, G,
                ob, last ? hb : ob, last ? 1 : 0);
        }
    }

    // ---- global add pool ----
    zero_f32<<<(NGR * D + 255) / 256, 256, 0, stream>>>(out, NGR * D);
    pool_kernel<<<(NN + PCH - 1) / PCH, 128, 0, stream>>>(hb, batch, out);
}